// Round 1
// baseline (280.132 us; speedup 1.0000x reference)
//
#include <hip/hip_runtime.h>
#include <hip/hip_bf16.h>
#include <math.h>

// InputSequenceNormalization: x[B,F,T] fp32, lengths[B] fp32.
// n_b = round(lengths[b]*T); per (b,f) row: mean/std over first n_b frames
// (std unbiased ddof=1, clamped at 1e-10), normalize ALL T frames.
//
// One block per (b,f) row. T=8000 -> 2000 float4; 256 threads -> 8 float4
// per thread held in registers so x is read from HBM exactly once.

#define ROW_T 8000
#define TV (ROW_T / 4)          // 2000 float4 per row
#define BLOCK 256
#define VPT 8                   // ceil(2000/256) = 8 float4 per thread
#define EPS 1e-10f

__device__ __forceinline__ float block_reduce_sum(float v, float* lds) {
    // wave64 shuffle reduce
    #pragma unroll
    for (int off = 32; off > 0; off >>= 1)
        v += __shfl_down(v, off, 64);
    const int wave = threadIdx.x >> 6;
    const int lane = threadIdx.x & 63;
    if (lane == 0) lds[wave] = v;
    __syncthreads();
    float r = (lds[0] + lds[1]) + (lds[2] + lds[3]);
    __syncthreads();
    return r;
}

__global__ __launch_bounds__(BLOCK) void isn_kernel(
        const float* __restrict__ x,
        const float* __restrict__ lengths,
        float* __restrict__ out,
        int F) {
    __shared__ float lds[4];

    const int row = blockIdx.x;            // row = b*F + f
    const int b = row / F;
    const float* __restrict__ xr = x + (size_t)row * ROW_T;
    float* __restrict__ outr = out + (size_t)row * ROW_T;
    const int tid = threadIdx.x;

    // valid frame count (jnp.round == rintf: half-to-even)
    const int n = (int)rintf(lengths[b] * (float)ROW_T);
    const float nf = (float)n;

    // ---- load row into registers (single HBM read of x) ----
    float4 v[VPT];
    #pragma unroll
    for (int it = 0; it < VPT; ++it) {
        const int idx = tid + it * BLOCK;
        if (idx < TV) v[it] = ((const float4*)xr)[idx];
    }

    // ---- pass 1: masked sum -> mean ----
    float s = 0.0f;
    #pragma unroll
    for (int it = 0; it < VPT; ++it) {
        const int base = (tid + it * BLOCK) * 4;
        if (base < ROW_T) {
            s += (base + 0 < n) ? v[it].x : 0.0f;
            s += (base + 1 < n) ? v[it].y : 0.0f;
            s += (base + 2 < n) ? v[it].z : 0.0f;
            s += (base + 3 < n) ? v[it].w : 0.0f;
        }
    }
    const float mean = block_reduce_sum(s, lds) / nf;

    // ---- pass 2: masked sum of squared deviations -> std ----
    float ss = 0.0f;
    #pragma unroll
    for (int it = 0; it < VPT; ++it) {
        const int base = (tid + it * BLOCK) * 4;
        if (base < ROW_T) {
            float dx = v[it].x - mean, dy = v[it].y - mean;
            float dz = v[it].z - mean, dw = v[it].w - mean;
            ss += (base + 0 < n) ? dx * dx : 0.0f;
            ss += (base + 1 < n) ? dy * dy : 0.0f;
            ss += (base + 2 < n) ? dz * dz : 0.0f;
            ss += (base + 3 < n) ? dw * dw : 0.0f;
        }
    }
    const float var = block_reduce_sum(ss, lds) / (nf - 1.0f);
    const float stdv = fmaxf(sqrtf(var), EPS);
    const float inv = 1.0f / stdv;

    // ---- pass 3: normalize ALL frames, store ----
    #pragma unroll
    for (int it = 0; it < VPT; ++it) {
        const int idx = tid + it * BLOCK;
        if (idx < TV) {
            float4 o;
            o.x = (v[it].x - mean) * inv;
            o.y = (v[it].y - mean) * inv;
            o.z = (v[it].z - mean) * inv;
            o.w = (v[it].w - mean) * inv;
            ((float4*)outr)[idx] = o;
        }
    }
}

extern "C" void kernel_launch(void* const* d_in, const int* in_sizes, int n_in,
                              void* d_out, int out_size, void* d_ws, size_t ws_size,
                              hipStream_t stream) {
    const float* x = (const float*)d_in[0];
    const float* lengths = (const float*)d_in[1];
    float* out = (float*)d_out;

    const int B = in_sizes[1];                     // 64
    const int F = in_sizes[0] / (B * ROW_T);       // 80
    const int rows = B * F;                        // 5120 blocks

    isn_kernel<<<rows, BLOCK, 0, stream>>>(x, lengths, out, F);
}

// Round 2
// 265.477 us; speedup vs baseline: 1.0552x; 1.0552x over previous
//
#include <hip/hip_runtime.h>
#include <hip/hip_bf16.h>
#include <math.h>

// InputSequenceNormalization: x[B,F,T] fp32, lengths[B] fp32.
// n_b = round(lengths[b]*T); per (b,f) row: mean/std over first n_b frames
// (std unbiased ddof=1, clamped at 1e-10), normalize ALL T frames.
//
// One block per (b,f) row, 512 threads, 4 float4/thread held in registers
// so x is read from HBM exactly once. Single fused (sum, sumsq) block
// reduction: var = (ss - s^2/n)/(n-1)  [fp32 error ~1e-5, threshold 0.109].
// Nontemporal loads/stores: x read once, out never re-read -> keep L2 clean.

#define ROW_T 8000
#define TV (ROW_T / 4)          // 2000 float4 per row
#define BLOCK 512
#define WAVES (BLOCK / 64)      // 8
#define VPT 4                   // ceil(2000/512) = 4 float4 per thread
#define EPS 1e-10f

typedef float v4f __attribute__((ext_vector_type(4)));

__global__ __launch_bounds__(BLOCK) void isn_kernel(
        const float* __restrict__ x,
        const float* __restrict__ lengths,
        float* __restrict__ out,
        int F) {
    __shared__ float2 lds[WAVES];

    const int row = blockIdx.x;            // row = b*F + f
    const int b = row / F;
    const v4f* __restrict__ xr = (const v4f*)(x + (size_t)row * ROW_T);
    v4f* __restrict__ outr = (v4f*)(out + (size_t)row * ROW_T);
    const int tid = threadIdx.x;

    // valid frame count (jnp.round == rintf: half-to-even)
    const int n = (int)rintf(lengths[b] * (float)ROW_T);
    const float nf = (float)n;

    // ---- load row into registers (single HBM read of x, nontemporal) ----
    v4f v[VPT];
    #pragma unroll
    for (int it = 0; it < VPT; ++it) {
        const int idx = tid + it * BLOCK;
        if (idx < TV) v[it] = __builtin_nontemporal_load(&xr[idx]);
    }

    // ---- fused masked sum + sumsq ----
    float s = 0.0f, ss = 0.0f;
    #pragma unroll
    for (int it = 0; it < VPT; ++it) {
        const int base = (tid + it * BLOCK) * 4;
        if (base < ROW_T) {
            #pragma unroll
            for (int j = 0; j < 4; ++j) {
                const float xv = (base + j < n) ? v[it][j] : 0.0f;
                s += xv;
                ss = fmaf(xv, xv, ss);
            }
        }
    }

    // ---- one block reduction of (s, ss) ----
    #pragma unroll
    for (int off = 32; off > 0; off >>= 1) {
        s  += __shfl_down(s, off, 64);
        ss += __shfl_down(ss, off, 64);
    }
    const int wave = tid >> 6;
    const int lane = tid & 63;
    if (lane == 0) lds[wave] = make_float2(s, ss);
    __syncthreads();
    float rs = 0.0f, rss = 0.0f;
    #pragma unroll
    for (int i = 0; i < WAVES; ++i) { rs += lds[i].x; rss += lds[i].y; }

    const float mean = rs / nf;
    const float var = (rss - rs * rs / nf) / (nf - 1.0f);
    const float stdv = fmaxf(sqrtf(var), EPS);
    const float inv = 1.0f / stdv;

    // ---- normalize ALL frames, nontemporal store ----
    #pragma unroll
    for (int it = 0; it < VPT; ++it) {
        const int idx = tid + it * BLOCK;
        if (idx < TV) {
            v4f o;
            #pragma unroll
            for (int j = 0; j < 4; ++j)
                o[j] = (v[it][j] - mean) * inv;
            __builtin_nontemporal_store(o, &outr[idx]);
        }
    }
}

extern "C" void kernel_launch(void* const* d_in, const int* in_sizes, int n_in,
                              void* d_out, int out_size, void* d_ws, size_t ws_size,
                              hipStream_t stream) {
    const float* x = (const float*)d_in[0];
    const float* lengths = (const float*)d_in[1];
    float* out = (float*)d_out;

    const int B = in_sizes[1];                     // 64
    const int F = in_sizes[0] / (B * ROW_T);       // 80
    const int rows = B * F;                        // 5120 blocks

    isn_kernel<<<rows, BLOCK, 0, stream>>>(x, lengths, out, F);
}